// Round 11
// baseline (1418.307 us; speedup 1.0000x reference)
//
#include <hip/hip_runtime.h>
#include <hip/hip_bf16.h>

#define NSWEEP_X 8
#define NSWEEP_W 12

typedef float v2f __attribute__((ext_vector_type(2)));

__device__ __forceinline__ void wavefence() {
    __builtin_amdgcn_wave_barrier();
    asm volatile("" ::: "memory");
}

// Packed fp32 (VOP3P) helpers — 2 fp32 per instruction.
__device__ __forceinline__ v2f pk_mul(v2f a, v2f b) {
    v2f d; asm("v_pk_mul_f32 %0, %1, %2" : "=v"(d) : "v"(a), "v"(b)); return d;
}
__device__ __forceinline__ v2f pk_add(v2f a, v2f b) {
    v2f d; asm("v_pk_add_f32 %0, %1, %2" : "=v"(d) : "v"(a), "v"(b)); return d;
}
__device__ __forceinline__ v2f pk_fma(v2f a, v2f b, v2f c) {
    v2f d; asm("v_pk_fma_f32 %0, %1, %2, %3" : "=v"(d) : "v"(a), "v"(b), "v"(c)); return d;
}

__device__ __forceinline__ float bperm(int addr, float v) {
    return __int_as_float(__builtin_amdgcn_ds_bpermute(addr, __float_as_int(v)));
}

// 4-accumulator dot of two 32-float columns held as v2f[16].
__device__ __forceinline__ float dot32(const v2f a[16], const v2f b[16]) {
    v2f s0 = pk_mul(a[0], b[0]), s1 = pk_mul(a[1], b[1]);
    v2f s2 = pk_mul(a[2], b[2]), s3 = pk_mul(a[3], b[3]);
#pragma unroll
    for (int i = 4; i < 16; i += 4) {
        s0 = pk_fma(a[i+0], b[i+0], s0);
        s1 = pk_fma(a[i+1], b[i+1], s1);
        s2 = pk_fma(a[i+2], b[i+2], s2);
        s3 = pk_fma(a[i+3], b[i+3], s3);
    }
    v2f s = pk_add(pk_add(s0, s1), pk_add(s2, s3));
    return s.x + s.y;
}

// ---- Dual-matrix one-sided Jacobi: each lane holds full columns of TWO
// independent matrices (a = M_even, b = M_odd); half-wave split supplies two
// more -> 4 matrices/wave. The two chains interleave at compile time: B's
// dot/trans hides A's bperm/trans latency (r10 post-mortem: lockstep waves
// alternate idle pipes; intra-wave ILP is immune to that).
// Rotation params computed UNCONDITIONALLY for both (trans chains overlap);
// applies stay branch-guarded (s_cbranch_execz skips issue in late sweeps).
// Local-tau update (r7-r10 proven): col' = c*col - s*prt, nn' = nn - t*cp,
// side-uniform, pair-symmetric. Absolute skip threshold (4e-6*nmax)^2 above
// fp32 dot noise -> all-skip early exit fires once converged.
// NOTE: m-loop ROLLED — full unroll spills (round-3 regression).
__device__ __forceinline__ void jacobi_dual(v2f a[16], v2f b[16], int lane, int nsweep) {
    const int lb = lane << 2;
    for (int sw = 0; sw < nsweep; ++sw) {
        float nnA = dot32(a, a);
        float nnB = dot32(b, b);
        float nmA = nnA, nmB = nnB;
#pragma unroll
        for (int mk = 16; mk >= 1; mk >>= 1) {
            nmA = fmaxf(nmA, __shfl_xor(nmA, mk));
            nmB = fmaxf(nmB, __shfl_xor(nmB, mk));
        }
        const float thrA = 1.6e-11f * nmA * nmA;   // (4e-6 * nmax)^2
        const float thrB = 1.6e-11f * nmB * nmB;

        int did = 0;
#pragma unroll 1
        for (int m = 1; m < 32; ++m) {
            const int addr = lb ^ (m << 2);  // stays within own 32-lane half
            v2f pA[16], pB[16];
#pragma unroll
            for (int i = 0; i < 16; i++) {
                pA[i].x = bperm(addr, a[i].x);
                pA[i].y = bperm(addr, a[i].y);
                pB[i].x = bperm(addr, b[i].x);
                pB[i].y = bperm(addr, b[i].y);
            }
            float onA = bperm(addr, nnA);
            float onB = bperm(addr, nnB);
            float cpA = dot32(a, pA);
            float cpB = dot32(b, pB);
            // params for both, unconditional (chains interleave; results only
            // consumed under the guards below, so inf/NaN in skip lanes is dead)
            float tauA = (onA - nnA) * __builtin_amdgcn_rcpf(2.0f * cpA);
            float tauB = (onB - nnB) * __builtin_amdgcn_rcpf(2.0f * cpB);
            float denA = fabsf(tauA) + __builtin_amdgcn_sqrtf(fmaf(tauA, tauA, 1.0f));
            float denB = fabsf(tauB) + __builtin_amdgcn_sqrtf(fmaf(tauB, tauB, 1.0f));
            float ttA = copysignf(__builtin_amdgcn_rcpf(denA), tauA);
            float ttB = copysignf(__builtin_amdgcn_rcpf(denB), tauB);
            float ctA = __builtin_amdgcn_rsqf(fmaf(ttA, ttA, 1.0f));
            float ctB = __builtin_amdgcn_rsqf(fmaf(ttB, ttB, 1.0f));
            if (cpA * cpA > thrA) {
                float msn = ttA * (-ctA);
                v2f cs2; cs2.x = ctA; cs2.y = ctA;
                v2f ms2; ms2.x = msn; ms2.y = msn;
#pragma unroll
                for (int i = 0; i < 16; i++)
                    a[i] = pk_fma(ms2, pA[i], pk_mul(cs2, a[i]));
                nnA = fmaxf(fmaf(-ttA, cpA, nnA), 0.0f);
                did = 1;
            }
            if (cpB * cpB > thrB) {
                float msn = ttB * (-ctB);
                v2f cs2; cs2.x = ctB; cs2.y = ctB;
                v2f ms2; ms2.x = msn; ms2.y = msn;
#pragma unroll
                for (int i = 0; i < 16; i++)
                    b[i] = pk_fma(ms2, pB[i], pk_mul(cs2, b[i]));
                nnB = fmaxf(fmaf(-ttB, cpB, nnB), 0.0f);
                did = 1;
            }
        }
        if (!__any(did)) break;   // all 4 matrices in the wave converged
    }
}

// Rank own column by sigma^2 (descending, tie-break index) within the 32-lane
// group; rk<8 lanes pack their column into P0m[rk*32 + h], sigma^2 into sigm.
__device__ __forceinline__ void rank_pack2(const v2f col[16], int jl,
                                           float* P0m, float* nrmm, float* sigm) {
    float nn = dot32(col, col);
    nrmm[jl] = nn;
    wavefence();
    int rk = 0;
    for (int k = 0; k < 32; k++) {
        float o = nrmm[k];
        rk += (o > nn) || (o == nn && k < jl);
    }
    if (rk < 8) {
#pragma unroll
        for (int i = 0; i < 16; i++)
            *(v2f*)&P0m[rk * 32 + 2 * i] = col[i];
        sigm[rk] = nn;
    }
    wavefence();
}

// single-matrix Jacobi (kept for the tiny w-kernel)
__device__ __forceinline__ void jacobi2(v2f col[16], int lane, int nsweep) {
    const int lb = lane << 2;
    for (int sw = 0; sw < nsweep; ++sw) {
        float nn = dot32(col, col);
        float nmax = nn;
#pragma unroll
        for (int mk = 16; mk >= 1; mk >>= 1) nmax = fmaxf(nmax, __shfl_xor(nmax, mk));
        const float thr = 1.6e-11f * nmax * nmax;
        int did = 0;
#pragma unroll 1
        for (int m = 1; m < 32; ++m) {
            const int addr = lb ^ (m << 2);
            v2f prt[16];
#pragma unroll
            for (int i = 0; i < 16; i++) {
                prt[i].x = bperm(addr, col[i].x);
                prt[i].y = bperm(addr, col[i].y);
            }
            float on = bperm(addr, nn);
            float cp = dot32(col, prt);
            if (cp * cp > thr) {
                float tau = (on - nn) * __builtin_amdgcn_rcpf(2.0f * cp);
                float den = fabsf(tau) + __builtin_amdgcn_sqrtf(fmaf(tau, tau, 1.0f));
                float tt  = copysignf(__builtin_amdgcn_rcpf(den), tau);
                float cth = __builtin_amdgcn_rsqf(fmaf(tt, tt, 1.0f));
                float msn = tt * (-cth);
                v2f cs2; cs2.x = cth; cs2.y = cth;
                v2f ms2; ms2.x = msn; ms2.y = msn;
#pragma unroll
                for (int i = 0; i < 16; i++)
                    col[i] = pk_fma(ms2, prt[i], pk_mul(cs2, col[i]));
                nn = fmaxf(fmaf(-tt, cp, nn), 0.0f);
                did = 1;
            }
        }
        if (!__any(did)) break;
    }
}

// ---- Kernel 1: SVD of w[c]; one wave per block handles TWO c channels.
__global__ __launch_bounds__(64)
void svd_w_kernel(const float* __restrict__ w, float* __restrict__ uwd,
                  float* __restrict__ vwt) {
    __shared__ float P0w[512];   // [hb*256 + mm*32 + h]
    __shared__ float nrmw[64];
    __shared__ float sigw[16];
    const int lane = threadIdx.x, jl = lane & 31, hb = lane >> 5;
    const int c = blockIdx.x * 2 + hb;

    v2f col[16], a0[16];
#pragma unroll
    for (int i = 0; i < 16; i++) {
        col[i].x = w[c * 1024 + (2 * i) * 32 + jl];
        col[i].y = w[c * 1024 + (2 * i + 1) * 32 + jl];
        a0[i] = col[i];
    }
    jacobi2(col, lane, NSWEEP_W);
    rank_pack2(col, jl, P0w + hb * 256, nrmw + hb * 32, sigw + hb * 8);

    for (int e = jl; e < 256; e += 32)
        uwd[c * 256 + e] = P0w[hb * 256 + (e & 7) * 32 + (e >> 3)];

#pragma unroll
    for (int mm = 0; mm < 8; mm++) {
        v2f p[16];
#pragma unroll
        for (int i = 0; i < 16; i++) p[i] = *(const v2f*)&P0w[hb * 256 + mm * 32 + 2 * i];
        float vq = dot32(a0, p);
        vq *= __builtin_amdgcn_rcpf(sigw[hb * 8 + mm]);
        vwt[c * 256 + jl * 8 + mm] = vq;
    }
}

// ---- Kernel 2: block = 4 waves = 16 matrices (16 c of one bt). grid 2048.
// No LDS staging (global strided loads; L3-resident input). Each wave: 4
// matrices via half-wave split x per-lane dual registers.
__global__ __launch_bounds__(256, 3)
void svd_main_kernel(const float* __restrict__ x, const float* __restrict__ uwd,
                     const float* __restrict__ vwt, float* __restrict__ out) {
    __shared__ float P0[4096];    // [mi*256 + mm*32 + h]
    __shared__ float nrm[512];    // [mi*32 + j]
    __shared__ float sig[128];    // [mi*8 + mm]
    __shared__ float OUT[4096];   // [mi*256 + i*32 + wj]  (8-row passes)

    const int t = threadIdx.x, widx = t >> 6, lane = t & 63;
    const int jl = lane & 31, hb = lane >> 5;
    const int bt = blockIdx.x & 1023, cg = blockIdx.x >> 10;
    const int miA = widx * 4 + hb * 2, miB = miA + 1;
    const int cA = cg * 16 + miA, cB = cg * 16 + miB;

    // columns straight from global: x[bt][h][jl][c], h stride 1024 floats
    const float* xbA = x + (size_t)bt * 32768 + (size_t)jl * 32 + cA;
    const float* xbB = x + (size_t)bt * 32768 + (size_t)jl * 32 + cB;
    v2f colA[16], colB[16];
#pragma unroll
    for (int i = 0; i < 16; i++) {
        colA[i].x = xbA[(2 * i) * 1024];
        colA[i].y = xbA[(2 * i + 1) * 1024];
        colB[i].x = xbB[(2 * i) * 1024];
        colB[i].y = xbB[(2 * i + 1) * 1024];
    }

    jacobi_dual(colA, colB, lane, NSWEEP_X);
    rank_pack2(colA, jl, P0 + miA * 256, nrm + miA * 32, sig + miA * 8);
    rank_pack2(colB, jl, P0 + miB * 256, nrm + miB * 32, sig + miB * 8);
    // cols dead; reload originals (L2/L3-hot) for V recovery

    float qvA[8], qvB[8];
    {
        v2f a0[16];
#pragma unroll
        for (int i = 0; i < 16; i++) {
            a0[i].x = xbA[(2 * i) * 1024];
            a0[i].y = xbA[(2 * i + 1) * 1024];
        }
        const float* vw = vwt + cA * 256;
#pragma unroll
        for (int mm = 0; mm < 8; mm++) {
            v2f p[16];
#pragma unroll
            for (int i = 0; i < 16; i++) p[i] = *(const v2f*)&P0[miA * 256 + mm * 32 + 2 * i];
            float vq = dot32(a0, p);
            vq *= __builtin_amdgcn_rcpf(sig[miA * 8 + mm]);
            qvA[mm] = vq * vw[jl * 8 + mm];
        }
    }
    {
        v2f a0[16];
#pragma unroll
        for (int i = 0; i < 16; i++) {
            a0[i].x = xbB[(2 * i) * 1024];
            a0[i].y = xbB[(2 * i + 1) * 1024];
        }
        const float* vw = vwt + cB * 256;
#pragma unroll
        for (int mm = 0; mm < 8; mm++) {
            v2f p[16];
#pragma unroll
            for (int i = 0; i < 16; i++) p[i] = *(const v2f*)&P0[miB * 256 + mm * 32 + 2 * i];
            float vq = dot32(a0, p);
            vq *= __builtin_amdgcn_rcpf(sig[miB * 8 + mm]);
            qvB[mm] = vq * vw[jl * 8 + mm];
        }
    }

    // Pg in place: P0[mi][mm*32+h] *= uw[h*8+mm]
    const float* uwA = uwd + cA * 256;
    const float* uwB = uwd + cB * 256;
    for (int e = jl; e < 256; e += 32) {
        P0[miA * 256 + e] *= uwA[(e & 31) * 8 + (e >> 5)];
        P0[miB * 256 + e] *= uwB[(e & 31) * 8 + (e >> 5)];
    }
    wavefence();

    // out[h][jl][c] = sum_mm Pg[h][mm]*qv[mm], four 8-row passes.
    float4* o4 = (float4*)out;
    const size_t obase = (size_t)bt * 8192 + cg * 4;
    for (int p = 0; p < 4; ++p) {
#pragma unroll
        for (int i = 0; i < 8; i++) {
            int h = p * 8 + i;
            float accA = 0.f, accB = 0.f;
#pragma unroll
            for (int mm = 0; mm < 8; mm++) {
                accA = fmaf(P0[miA * 256 + mm * 32 + h], qvA[mm], accA);
                accB = fmaf(P0[miB * 256 + mm * 32 + h], qvB[mm], accB);
            }
            OUT[miA * 256 + i * 32 + jl] = accA;
            OUT[miB * 256 + i * 32 + jl] = accB;
        }
        __syncthreads();
        {
            int hh = t >> 5, wj = t & 31;         // 8 rows x 32 cols
            int h = p * 8 + hh;
#pragma unroll
            for (int q = 0; q < 4; q++) {
                float4 v = make_float4(OUT[(4 * q + 0) * 256 + hh * 32 + wj],
                                       OUT[(4 * q + 1) * 256 + hh * 32 + wj],
                                       OUT[(4 * q + 2) * 256 + hh * 32 + wj],
                                       OUT[(4 * q + 3) * 256 + hh * 32 + wj]);
                o4[obase + (size_t)h * 256 + (size_t)wj * 8 + q] = v;
            }
        }
        if (p < 3) __syncthreads();   // gather done before next pass rewrite
    }
}

extern "C" void kernel_launch(void* const* d_in, const int* in_sizes, int n_in,
                              void* d_out, int out_size, void* d_ws, size_t ws_size,
                              hipStream_t stream) {
    (void)in_sizes; (void)n_in; (void)out_size; (void)ws_size;
    const float* x = (const float*)d_in[0];
    const float* w = (const float*)d_in[1];
    float* out = (float*)d_out;
    float* uwd = (float*)d_ws;            // [32][32][8]
    float* vwt = uwd + 32 * 256;          // [32][32][8]

    hipLaunchKernelGGL(svd_w_kernel, dim3(16), dim3(64), 0, stream, w, uwd, vwt);
    hipLaunchKernelGGL(svd_main_kernel, dim3(2048), dim3(256), 0, stream, x, uwd, vwt, out);
}